// Round 1
// baseline (183.332 us; speedup 1.0000x reference)
//
#include <hip/hip_runtime.h>
#include <hip/hip_bf16.h>
#include <stdint.h>

// Problem constants
#define B_ 16
#define C_ 256
#define H_ 64
#define W_ 64
#define WP 66                 // padded width: w' = w+1, border cols 0 and 65 are zero
#define ROWB (WP * C_ * 2)    // bytes per padded (b,h) row of bf16 signs = 33792

typedef unsigned short u16;
typedef __attribute__((ext_vector_type(8))) short short8;   // 8 bf16 = 4 VGPRs (MFMA A/B frag)
typedef __attribute__((ext_vector_type(4))) float f32x4;    // MFMA C/D frag

typedef const __attribute__((address_space(1))) uint32_t* gptr_t;
typedef __attribute__((address_space(3))) uint32_t* lptr_t;

__device__ __forceinline__ void gl_lds16(const void* g, void* l) {
  // async global->LDS, 16B per lane; LDS dest = wave-uniform base + lane*16
  __builtin_amdgcn_global_load_lds((gptr_t)g, (lptr_t)l, 16, 0, 0);
}

__device__ __forceinline__ u16 sgn_bf16(float v) {
  return v > 0.f ? (u16)0x3F80 : (v < 0.f ? (u16)0xBF80 : (u16)0);
}

// ---------- kernel A: weight scale + binarized signs wtb[tap][o][c] ----------
__global__ void prep_w(const float* __restrict__ w, float* __restrict__ scale,
                       u16* __restrict__ wtb) {
  int o = blockIdx.x, tid = threadIdx.x;     // 256 threads; c = tid
  const float* wo = w + (size_t)o * 2304 + (size_t)tid * 9;  // w[o][c][kh][kw]
  float v[9];
  float s = 0.f;
#pragma unroll
  for (int t = 0; t < 9; ++t) { v[t] = wo[t]; s += fabsf(v[t]); }
  __shared__ float red[256];
  red[tid] = s;
  __syncthreads();
  for (int st = 128; st > 0; st >>= 1) {
    if (tid < st) red[tid] += red[tid + st];
    __syncthreads();
  }
  if (tid == 0) scale[o] = red[0] / 2304.0f;
#pragma unroll
  for (int t = 0; t < 9; ++t)
    wtb[(size_t)t * (C_ * C_) + (size_t)o * C_ + tid] = sgn_bf16(v[t]);
}

// ---------- kernel B: binarize + transpose to swizzled padded layout ----------
// a_p layout: for (b,h): row of WP=66 pixels; per pixel w' a 512B block of 256 bf16 c-values,
// with 16B chunks XOR-swizzled: chunk_stored = chunk ^ (w' & 31). Border w'=0,65 zero.
__global__ void binarize(const float* __restrict__ x, const float* __restrict__ bias,
                         uint8_t* __restrict__ a_p) {
  int bh = blockIdx.x, b = bh >> 6, h = bh & 63, c0 = blockIdx.y * 64;
  int tid = threadIdx.x;
  __shared__ u16 lt[64][68];  // [w][ci], stride 68 avoids write conflicts mostly
#pragma unroll
  for (int p = 0; p < 4; ++p) {
    int ci = p * 16 + (tid >> 4), w4 = (tid & 15) * 4;
    f32x4 v = *(const f32x4*)(x + (((size_t)(b * C_ + c0 + ci) * H_ + h) * W_ + w4));
    float bb = bias[c0 + ci];
#pragma unroll
    for (int k = 0; k < 4; ++k) lt[w4 + k][ci] = sgn_bf16(v[k] + bb);
  }
  __syncthreads();
  size_t rowbase = (size_t)(b * H_ + h) * ROWB;
#pragma unroll
  for (int p = 0; p < 4; ++p) {
    int w = p * 16 + (tid >> 4), cp = (tid & 15) * 4;
    uint64_t val = (uint64_t)lt[w][cp] | ((uint64_t)lt[w][cp + 1] << 16) |
                   ((uint64_t)lt[w][cp + 2] << 32) | ((uint64_t)lt[w][cp + 3] << 48);
    int wp = w + 1;
    int cb = (c0 + cp) * 2;  // byte offset within 512B pixel block (multiple of 8)
    int pos = wp * 512 + ((((cb >> 4) ^ wp) & 31) << 4) + (cb & 15);
    *(uint64_t*)(a_p + rowbase + pos) = val;
  }
  if (blockIdx.y == 0) {  // zero the two border pixels (any permutation of zeros is zeros)
    if (tid < 128) ((uint32_t*)(a_p + rowbase))[tid] = 0;
    else ((uint32_t*)(a_p + rowbase + 65 * 512))[tid - 128] = 0;
  }
}

// ---------- kernel C: binary conv via MFMA + fused epilogue ----------
// Block = one (b,h) row: M=256 output channels, N=64 pixels, K=2304.
// 4 waves; wave wv owns o in [wv*64, wv*64+64). acc[4][4] of 16x16 tiles.
__global__ __launch_bounds__(256) void bconv(
    const uint8_t* __restrict__ a_p, const u16* __restrict__ wtb,
    const float* __restrict__ scale, const float* __restrict__ x,
    const float* __restrict__ pb0, const float* __restrict__ alpha,
    const float* __restrict__ pb1, float* __restrict__ out) {
  __shared__ __attribute__((aligned(16))) uint8_t smem[ROWB];
  int bh = blockIdx.x, b = bh >> 6, h = bh & 63;
  int tid = threadIdx.x, l = tid & 63, wv = tid >> 6;
  int lm = l & 15, lk = l >> 4;
  int wm = wv * 64;

  f32x4 acc[4][4];
#pragma unroll
  for (int i = 0; i < 4; ++i)
#pragma unroll
    for (int j = 0; j < 4; ++j) acc[i][j] = (f32x4){0.f, 0.f, 0.f, 0.f};

  for (int dy = -1; dy <= 1; ++dy) {
    int r = h + dy;
    if (r < 0 || r >= H_) continue;  // uniform per block
    __syncthreads();                 // prior reads of smem done before overwrite
    const uint8_t* src = a_p + (size_t)(b * H_ + r) * ROWB;
#pragma unroll
    for (int it = 0; it < 8; ++it)
      gl_lds16(src + (size_t)(it * 256 + tid) * 16, smem + it * 4096 + wv * 1024);
    if (wv == 0) gl_lds16(src + (size_t)(2048 + l) * 16, smem + 32768);
    asm volatile("s_waitcnt vmcnt(0)" ::: "memory");
    __syncthreads();

#pragma unroll
    for (int dxi = 0; dxi < 3; ++dxi) {
      const u16* wt_t = wtb + (size_t)((dy + 1) * 3 + dxi) * (C_ * C_);
      for (int kc = 0; kc < 8; ++kc) {
        short8 af[4], bfr[4];
#pragma unroll
        for (int mi = 0; mi < 4; ++mi)
          af[mi] = *(const short8*)(wt_t + (size_t)(wm + mi * 16 + lm) * C_ + kc * 32 + lk * 8);
#pragma unroll
        for (int ni = 0; ni < 4; ++ni) {
          int wp = ni * 16 + lm + dxi;              // input pixel w' = w + dx + 1
          int cb = kc * 64 + lk * 16;               // byte offset of 8 bf16 c-values
          int pos = wp * 512 + ((((cb >> 4) ^ wp) & 31) << 4);
          bfr[ni] = *(const short8*)(smem + pos);
        }
#pragma unroll
        for (int mi = 0; mi < 4; ++mi)
#pragma unroll
          for (int ni = 0; ni < 4; ++ni)
            acc[mi][ni] = __builtin_amdgcn_mfma_f32_16x16x32_bf16(
                af[mi], bfr[ni], acc[mi][ni], 0, 0, 0);
      }
    }
  }

  // epilogue: conv*scale + pb0 -> PReLU -> + pb1 + x (residual)
  size_t xb = (size_t)b * C_ * H_ * W_ + (size_t)h * W_;
#pragma unroll
  for (int mi = 0; mi < 4; ++mi) {
#pragma unroll
    for (int j = 0; j < 4; ++j) {
      int o = wm + mi * 16 + lk * 4 + j;  // C/D row = (lane>>4)*4 + reg
      float sc = scale[o], b0 = pb0[o], al = alpha[o], b1 = pb1[o];
      size_t rowo = xb + (size_t)o * (H_ * W_);
#pragma unroll
      for (int ni = 0; ni < 4; ++ni) {
        int wcol = ni * 16 + lm;          // C/D col = lane&15
        float v = acc[mi][ni][j] * sc + b0;
        v = v >= 0.f ? v : al * v;
        v = v + b1 + x[rowo + wcol];
        out[rowo + wcol] = v;
      }
    }
  }
}

extern "C" void kernel_launch(void* const* d_in, const int* in_sizes, int n_in,
                              void* d_out, int out_size, void* d_ws, size_t ws_size,
                              hipStream_t stream) {
  const float* x     = (const float*)d_in[0];
  const float* m0b   = (const float*)d_in[1];
  const float* w     = (const float*)d_in[2];
  const float* pb0   = (const float*)d_in[3];
  const float* alpha = (const float*)d_in[4];
  const float* pb1   = (const float*)d_in[5];
  float* out = (float*)d_out;

  // ws layout: [0,1KB) scale | [4096, +1179648) wtb bf16 | a_p padded signs (34.6MB)
  // total needed ~= 35.8 MB
  float* scale = (float*)d_ws;
  u16* wtb = (u16*)((uint8_t*)d_ws + 4096);
  uint8_t* a_p = (uint8_t*)d_ws + 4096 + (size_t)9 * C_ * C_ * 2;

  hipLaunchKernelGGL(prep_w, dim3(C_), dim3(256), 0, stream, w, scale, wtb);
  hipLaunchKernelGGL(binarize, dim3(B_ * H_, C_ / 64), dim3(256), 0, stream, x, m0b, a_p);
  hipLaunchKernelGGL(bconv, dim3(B_ * H_), dim3(256), 0, stream,
                     a_p, wtb, scale, x, pb0, alpha, pb1, out);
}

// Round 2
// 157.285 us; speedup vs baseline: 1.1656x; 1.1656x over previous
//
#include <hip/hip_runtime.h>
#include <hip/hip_bf16.h>
#include <stdint.h>

// Problem constants
#define B_ 16
#define C_ 256
#define H_ 64
#define W_ 64
#define WP 66                  // padded width: w' = w+1, border cols 0 and 65 zero
#define ROWB (WP * C_)         // bytes per padded (b,h) row of fp8 signs = 16896
#define ROWB_AL 17408          // staged LDS size (row + 512B overrun pad)

typedef unsigned short u16;
typedef __attribute__((ext_vector_type(4))) float f32x4;

typedef const __attribute__((address_space(1))) uint32_t* gptr_t;
typedef __attribute__((address_space(3))) uint32_t* lptr_t;

__device__ __forceinline__ void gl_lds16(const void* g, void* l) {
  __builtin_amdgcn_global_load_lds((gptr_t)g, (lptr_t)l, 16, 0, 0);
}

// fp8 e4m3fn signs: +1 = 0x38, -1 = 0xB8, 0 = 0x00 (exact)
__device__ __forceinline__ uint8_t sgn8(float v) {
  return v > 0.f ? (uint8_t)0x38 : (v < 0.f ? (uint8_t)0xB8 : (uint8_t)0);
}

// ---------- kernel A: weight scale + fp8 signs in wave-linear layout ----------
// wtb[t][ot][kc][mi][lane][j] : o = ot*64 + mi*16 + (lane&15), c = kc*32 + (lane>>4)*8 + j
__global__ void prep_w(const float* __restrict__ w, float* __restrict__ scale,
                       uint8_t* __restrict__ wtb) {
  int o = blockIdx.x, c = threadIdx.x;
  const float* wo = w + (size_t)o * 2304 + (size_t)c * 9;  // w[o][c][kh][kw]
  float v[9];
  float s = 0.f;
#pragma unroll
  for (int t = 0; t < 9; ++t) { v[t] = wo[t]; s += fabsf(v[t]); }
  __shared__ float red[256];
  red[c] = s;
  __syncthreads();
  for (int st = 128; st > 0; st >>= 1) {
    if (c < st) red[c] += red[c + st];
    __syncthreads();
  }
  if (c == 0) scale[o] = red[0] / 2304.0f;
  int ot = o >> 6, mi = (o >> 4) & 3, lm = o & 15;
  int kc = c >> 5, lk = (c >> 3) & 3, j = c & 7, l = lk * 16 + lm;
#pragma unroll
  for (int t = 0; t < 9; ++t)
    wtb[((((size_t)t * 4 + ot) * 8 + kc) * 4 + mi) * 512 + l * 8 + j] = sgn8(v[t]);
}

// ---------- kernel B: binarize + transpose to swizzled padded fp8 layout ----------
// a_p per (b,h): 66 pixel-blocks of 256B; 8B chunks XOR-swizzled: stored_chunk = chunk ^ (w'&31)
__global__ void binarize(const float* __restrict__ x, const float* __restrict__ bias,
                         uint8_t* __restrict__ a_p) {
  int bh = blockIdx.x, b = bh >> 6, h = bh & 63, c0 = blockIdx.y * 64;
  int tid = threadIdx.x;
  __shared__ uint8_t lt[64][72];  // [w][ci]
#pragma unroll
  for (int p = 0; p < 4; ++p) {
    int ci = p * 16 + (tid >> 4), w4 = (tid & 15) * 4;
    f32x4 v = *(const f32x4*)(x + (((size_t)(b * C_ + c0 + ci) * H_ + h) * W_ + w4));
    float bb = bias[c0 + ci];
#pragma unroll
    for (int k = 0; k < 4; ++k) lt[w4 + k][ci] = sgn8(v[k] + bb);
  }
  __syncthreads();
  size_t rowbase = (size_t)(b * H_ + h) * ROWB;
#pragma unroll
  for (int p = 0; p < 4; ++p) {
    int w = p * 16 + (tid >> 4), cp = (tid & 15) * 4, c = c0 + cp;
    uint32_t val = (uint32_t)lt[w][cp] | ((uint32_t)lt[w][cp + 1] << 8) |
                   ((uint32_t)lt[w][cp + 2] << 16) | ((uint32_t)lt[w][cp + 3] << 24);
    int wp = w + 1;
    int pos = wp * 256 + ((((c >> 3) ^ wp) & 31) << 3) + (c & 7);
    *(uint32_t*)(a_p + rowbase + pos) = val;
  }
  if (blockIdx.y == 0) {  // zero border pixels (zeros are swizzle-invariant)
    if (tid < 64) *(uint32_t*)(a_p + rowbase + tid * 4) = 0;
    else if (tid < 128) *(uint32_t*)(a_p + rowbase + 65 * 256 + (tid - 64) * 4) = 0;
  }
}

// ---------- kernel C: binary conv via fp8 MFMA, software-pipelined ----------
#define LOADW(dst, t, kc)                                                         \
  _Pragma("unroll") for (int mi = 0; mi < 4; ++mi)                                \
      dst[mi] = *(const long*)(wtb + ((((size_t)(t) * 4 + wv) * 8 + (kc)) * 4 + mi) * 512 + l * 8);

#define LOADB(dst, dxi, kc)                                                       \
  _Pragma("unroll") for (int ni = 0; ni < 4; ++ni) {                              \
    int wp_ = ni * 16 + lm + (dxi);                                               \
    int ch_ = ((kc)*4 + lk) ^ wp_;                                                \
    dst[ni] = *(const long*)(smem + wp_ * 256 + ((ch_ & 31) << 3));               \
  }

__global__ __launch_bounds__(256, 4) void bconv(
    const uint8_t* __restrict__ a_p, const uint8_t* __restrict__ wtb,
    const float* __restrict__ scale, const float* __restrict__ x,
    const float* __restrict__ pb0, const float* __restrict__ alpha,
    const float* __restrict__ pb1, float* __restrict__ out) {
  __shared__ __attribute__((aligned(16))) uint8_t smem[ROWB_AL];
  int bh = blockIdx.x, b = bh >> 6, h = bh & 63;
  int tid = threadIdx.x, l = tid & 63, wv = tid >> 6;
  int lm = l & 15, lk = l >> 4;
  int wm = wv * 64;

  f32x4 acc[4][4];
#pragma unroll
  for (int i = 0; i < 4; ++i)
#pragma unroll
    for (int j = 0; j < 4; ++j) acc[i][j] = (f32x4){0.f, 0.f, 0.f, 0.f};

  for (int dy = -1; dy <= 1; ++dy) {
    int r = h + dy;
    if (r < 0 || r >= H_) continue;  // uniform per block
    __syncthreads();                 // finish prior reads before overwrite
    const uint8_t* src = a_p + (size_t)(b * H_ + r) * ROWB;
#pragma unroll
    for (int it = 0; it < 4; ++it)
      gl_lds16(src + (size_t)(it * 256 + tid) * 16, smem + it * 4096 + wv * 1024);
    if (wv == 0) gl_lds16(src + (size_t)(1024 + l) * 16, smem + 16384);  // 512B + pad overrun
    asm volatile("s_waitcnt vmcnt(0)" ::: "memory");
    __syncthreads();

    int tbase = (dy + 1) * 3;
    long afc[4], bfc[4];
    LOADW(afc, tbase, 0)
    LOADB(bfc, 0, 0)
#pragma unroll
    for (int i = 0; i < 24; ++i) {       // i = dxi*8 + kc
      long afn[4], bfn[4];
      if (i < 23) {
        int ii = i + 1, dxi = ii >> 3, kc = ii & 7;
        LOADW(afn, tbase + dxi, kc)
        LOADB(bfn, dxi, kc)
      }
#pragma unroll
      for (int mi = 0; mi < 4; ++mi)
#pragma unroll
        for (int ni = 0; ni < 4; ++ni)
          acc[mi][ni] = __builtin_amdgcn_mfma_f32_16x16x32_fp8_fp8(
              afc[mi], bfc[ni], acc[mi][ni], 0, 0, 0);
#pragma unroll
      for (int q = 0; q < 4; ++q) { afc[q] = afn[q]; bfc[q] = bfn[q]; }
    }
  }

  // epilogue: conv*scale + pb0 -> PReLU -> + pb1 + x (residual)
  size_t xb = (size_t)b * C_ * H_ * W_ + (size_t)h * W_;
#pragma unroll
  for (int mi = 0; mi < 4; ++mi) {
#pragma unroll
    for (int j = 0; j < 4; ++j) {
      int o = wm + mi * 16 + lk * 4 + j;  // C/D row = (lane>>4)*4 + reg
      float sc = scale[o], b0 = pb0[o], al = alpha[o], b1 = pb1[o];
      size_t rowo = xb + (size_t)o * (H_ * W_);
#pragma unroll
      for (int ni = 0; ni < 4; ++ni) {
        int wcol = ni * 16 + lm;          // C/D col = lane&15
        float v = acc[mi][ni][j] * sc + b0;
        v = v >= 0.f ? v : al * v;
        v = v + b1 + x[rowo + wcol];
        out[rowo + wcol] = v;
      }
    }
  }
}

extern "C" void kernel_launch(void* const* d_in, const int* in_sizes, int n_in,
                              void* d_out, int out_size, void* d_ws, size_t ws_size,
                              hipStream_t stream) {
  const float* x     = (const float*)d_in[0];
  const float* m0b   = (const float*)d_in[1];
  const float* w     = (const float*)d_in[2];
  const float* pb0   = (const float*)d_in[3];
  const float* alpha = (const float*)d_in[4];
  const float* pb1   = (const float*)d_in[5];
  float* out = (float*)d_out;

  // ws: [0,1KB) scale | [4096, +589824) wtb fp8 | [593920, +17.3MB+pad) a_p
  float* scale = (float*)d_ws;
  uint8_t* wtb = (uint8_t*)d_ws + 4096;
  uint8_t* a_p = (uint8_t*)d_ws + 4096 + (size_t)9 * 4 * 8 * 4 * 512;

  hipLaunchKernelGGL(prep_w, dim3(C_), dim3(256), 0, stream, w, scale, wtb);
  hipLaunchKernelGGL(binarize, dim3(B_ * H_, C_ / 64), dim3(256), 0, stream, x, m0b, a_p);
  hipLaunchKernelGGL(bconv, dim3(B_ * H_), dim3(256), 0, stream,
                     a_p, wtb, scale, x, pb0, alpha, pb1, out);
}